// Round 6
// baseline (16.389 us; speedup 1.0000x reference)
//
#include <hip/hip_runtime.h>
#include <math.h>

#define NT 256

__device__ __forceinline__ float sigmoid_f(float v) {
    return 1.0f / (1.0f + expf(-v));
}

__device__ __forceinline__ float quant_f(float z) {
    // first-occurrence argmin over |z - c| (strict < keeps earliest code on tie)
    float best = 0.25f;
    float bd = fabsf(z - 0.25f);
    const float cbs[8] = {0.3536f, 0.5f, 0.7071f, 1.0f, 1.4142f, 2.0f, 2.8284f, 4.0f};
#pragma unroll
    for (int i = 0; i < 8; i++) {
        float d = fabsf(z - cbs[i]);
        if (d < bd) { bd = d; best = cbs[i]; }
    }
    return best;
}

// dot of weight-registers (static-indexed) against an LDS vector read as float4
template<int N4>
__device__ __forceinline__ float dot_rl(const float* wr, const float* v) {
    const float4* v4 = (const float4*)v;
    float a0 = 0.f, a1 = 0.f, a2 = 0.f, a3 = 0.f;
#pragma unroll
    for (int i = 0; i < N4; i++) {
        float4 vv = v4[i];
        a0 = fmaf(wr[4*i+0], vv.x, a0);
        a1 = fmaf(wr[4*i+1], vv.y, a1);
        a2 = fmaf(wr[4*i+2], vv.z, a2);
        a3 = fmaf(wr[4*i+3], vv.w, a3);
    }
    return (a0 + a1) + (a2 + a3);
}

__device__ __forceinline__ int sliceStart(int g) {  // 100-wide operand slices 28/24/24/24
    return g == 0 ? 0 : (g == 1 ? 28 : (g == 2 ? 52 : 76));
}

__global__ __launch_bounds__(NT, 1) void cvae_kernel(
    const float* __restrict__ x, const float* __restrict__ y, const float* __restrict__ eps,
    const float* __restrict__ W1, const float* __restrict__ b1,
    const float* __restrict__ W2m, const float* __restrict__ b2m,
    const float* __restrict__ W2s, const float* __restrict__ b2s,
    const float* __restrict__ W3, const float* __restrict__ b3,
    const float* __restrict__ W4, const float* __restrict__ b4,
    const float* __restrict__ W5, const float* __restrict__ b5,
    const float* __restrict__ W6, const float* __restrict__ b6,
    float* __restrict__ out)
{
    const int tid = threadIdx.x;

    // activation LDS; all slice bases 16B-aligned
    __shared__ __align__(16) float cat0[20];       // enc input cols 0..19
    __shared__ __align__(16) float cat1[20];       // enc input cols 20..37 (+2 zero)
    __shared__ __align__(16) float cat2v[40];      // dec input [z(28)|y(10)|0,0]
    __shared__ __align__(16) float h_lds[4][28];   // fc1/fc3 output, slices 28/24/24/24 (+pad zeros)
    __shared__ __align__(16) float rec4[4][32];    // recon vec per decoder step (only [0..27] read)
    __shared__ __align__(16) float t_b[4][112];    // batched fc5 outputs (cols 100..111 zero)
    __shared__ __align__(16) float ostash[364];    // deferred output mirror (no global writes mid-kernel)

    // ---- lane roles (fixed per thread) ----
    const int r1 = tid >> 1, p1 = tid & 1;        // E1 (W1): 2 lanes/row, tid<200
    const int r2 = tid >> 3, c2 = tid & 7;        // E2E3: 8 lanes/row, tid<224
    const int g2 = c2 & 3;
    const int r4 = tid >> 2, g4 = tid & 3;        // A (W4): 4 lanes/row, tid<112
    const int r3 = tid - 128;                     // fc3 (W3): 1 lane/row, 128<=tid<228
    const int s3lo = (tid >= 100) ? 1 : 0;        // fc5 batch: tid<200
    const int j5 = tid - 100 * s3lo;
    const int idx6 = tid >> 1, p6 = tid & 1;      // fc6 batch: tid<224
    const int s36 = idx6 / 28, i6 = idx6 - 28 * s36;

    // destination offsets into h_lds (flat) for the 100-entry outputs
    const int hg  = (r1 < 28) ? 0 : ((r1 < 52) ? 1 : ((r1 < 76) ? 2 : 3));
    const int ho  = hg * 28 + (r1 - sliceStart(hg));
    const int h3g = (r3 < 28) ? 0 : ((r3 < 52) ? 1 : ((r3 < 76) ? 2 : 3));
    const int h3o = h3g * 28 + (r3 - sliceStart(h3g));

    // ---- weight/bias/eps loads into registers (once; L2-hot on replays) ----
    float w1s[20]; float b1r = 0.f;
    if (tid < 200) {
        const float2* s2 = (const float2*)(W1 + r1 * 38 + p1 * 20);  // even offset -> 8B aligned
        if (p1 == 0) {
#pragma unroll
            for (int i = 0; i < 10; i++) { float2 v = s2[i]; w1s[2*i] = v.x; w1s[2*i+1] = v.y; }
            b1r = b1[r1];
        } else {
#pragma unroll
            for (int i = 0; i < 9; i++) { float2 v = s2[i]; w1s[2*i] = v.x; w1s[2*i+1] = v.y; }
            w1s[18] = 0.f; w1s[19] = 0.f;
        }
    }

    float w2s[28]; float b2r = 0.f; float er[4] = {0.f, 0.f, 0.f, 0.f};
    if (tid < 224) {
        const float* mat = (c2 < 4) ? W2m : W2s;
        const float4* s4 = (const float4*)(mat + r2 * 100 + sliceStart(g2));  // starts 0/28/52/76: 16B aligned
        if (g2 == 0) {
#pragma unroll
            for (int i = 0; i < 7; i++) { float4 v = s4[i]; w2s[4*i] = v.x; w2s[4*i+1] = v.y; w2s[4*i+2] = v.z; w2s[4*i+3] = v.w; }
        } else {
#pragma unroll
            for (int i = 0; i < 6; i++) { float4 v = s4[i]; w2s[4*i] = v.x; w2s[4*i+1] = v.y; w2s[4*i+2] = v.z; w2s[4*i+3] = v.w; }
            w2s[24] = 0.f; w2s[25] = 0.f; w2s[26] = 0.f; w2s[27] = 0.f;
        }
        if (c2 == 0) {
            b2r = b2m[r2];
            er[0] = eps[r2]; er[1] = eps[28 + r2]; er[2] = eps[56 + r2]; er[3] = eps[84 + r2];
        }
        if (c2 == 4) b2r = b2s[r2];
    }

    float w4s[28]; float b4r = 0.f;
    if (tid < 112) {
        const float4* s4 = (const float4*)(W4 + r4 * 100 + sliceStart(g4));
        if (g4 == 0) {
#pragma unroll
            for (int i = 0; i < 7; i++) { float4 v = s4[i]; w4s[4*i] = v.x; w4s[4*i+1] = v.y; w4s[4*i+2] = v.z; w4s[4*i+3] = v.w; }
            b4r = b4[r4];
        } else {
#pragma unroll
            for (int i = 0; i < 6; i++) { float4 v = s4[i]; w4s[4*i] = v.x; w4s[4*i+1] = v.y; w4s[4*i+2] = v.z; w4s[4*i+3] = v.w; }
            w4s[24] = 0.f; w4s[25] = 0.f; w4s[26] = 0.f; w4s[27] = 0.f;
        }
    }

    // fc5 batch: full W5 row j5 (28 floats)
    float w5f[28]; float b5r = 0.f;
    if (tid < 200) {
        const float4* s4 = (const float4*)(W5 + j5 * 28);   // 28 % 4 == 0 -> 16B aligned
#pragma unroll
        for (int i = 0; i < 7; i++) { float4 v = s4[i]; w5f[4*i] = v.x; w5f[4*i+1] = v.y; w5f[4*i+2] = v.z; w5f[4*i+3] = v.w; }
        b5r = b5[j5];
    }

    // fc6 batch: half W6 row i6 (cols 52*p6 ..), K-split 52/48(+4 zero)
    float w6h[52]; float b6r = 0.f;
    if (tid < 224) {
        const float4* s4 = (const float4*)(W6 + i6 * 100 + 52 * p6);  // 16B aligned
        if (p6 == 0) {
#pragma unroll
            for (int i = 0; i < 13; i++) { float4 v = s4[i]; w6h[4*i] = v.x; w6h[4*i+1] = v.y; w6h[4*i+2] = v.z; w6h[4*i+3] = v.w; }
            b6r = b6[i6];
        } else {
#pragma unroll
            for (int i = 0; i < 12; i++) { float4 v = s4[i]; w6h[4*i] = v.x; w6h[4*i+1] = v.y; w6h[4*i+2] = v.z; w6h[4*i+3] = v.w; }
            w6h[48] = 0.f; w6h[49] = 0.f; w6h[50] = 0.f; w6h[51] = 0.f;
        }
    }

    float w3s[40]; float b3r = 0.f;
    if (tid >= 128 && tid < 228) {
        const float2* s2 = (const float2*)(W3 + r3 * 38);  // even offset
#pragma unroll
        for (int i = 0; i < 19; i++) { float2 v = s2[i]; w3s[2*i] = v.x; w3s[2*i+1] = v.y; }
        w3s[38] = 0.f; w3s[39] = 0.f;
        b3r = b3[r3];
    }

    // ---- LDS init ----
    if (tid < 28) {
        float xv = x[tid];
        if (tid < 20) cat0[tid] = xv; else cat1[tid - 20] = xv;
        ostash[112 + tid] = 0.f;   // mu_e row 3
        ostash[336 + tid] = 0.f;   // logstd row 3
    }
    if (tid < 10) { float yv = y[tid]; cat1[8 + tid] = yv; cat2v[28 + tid] = yv; }
    if (tid == 0) { cat1[18] = 0.f; cat1[19] = 0.f; cat2v[38] = 0.f; cat2v[39] = 0.f; }
    if (tid >= 1 && tid < 4) {
#pragma unroll
        for (int j = 24; j < 28; j++) h_lds[tid][j] = 0.f;
    }
    if (tid >= 32 && tid < 96) {   // zero t_b cols 96..111 (96-99 later overwritten by fc5)
        int r = (tid - 32) >> 4, c = 96 + ((tid - 32) & 15);
        t_b[r][c] = 0.f;
    }
    __syncthreads();

    // ---- encoder: 4 levels x 2 stages (no global writes -> no vmcnt drain at barriers) ----
#pragma unroll
    for (int lev = 0; lev < 4; lev++) {
        // E1: h = relu(W1 @ cat + b1), 2 lanes/row over all 4 waves
        if (tid < 200) {
            float s = dot_rl<5>(w1s, p1 ? cat1 : cat0);
            s += __shfl_xor(s, 1);
            if (p1 == 0) ((float*)h_lds)[ho] = fmaxf(s + b1r, 0.f);
        }
        __syncthreads();

        // E2+E3 fused: 8 lanes/row (4 mu + 4 ls), shfl-reduce, quant inline
        if (tid < 224) {
            float s = dot_rl<7>(w2s, h_lds[g2]);
            s += __shfl_xor(s, 1);
            s += __shfl_xor(s, 2);
            float fin = 0.f;
            if (c2 == 0)      fin = s + b2r;               // mu[r2]
            else if (c2 == 4) fin = sigmoid_f(s + b2r);    // ls[r2]
            float oth = __shfl_xor(fin, 4);                // c0 gets ls, c4 gets mu (same r2)
            if (c2 == 0) {
                float z = quant_f(fmaf(er[lev], oth, fin));
                if (r2 < 20) cat0[r2] = z; else cat1[r2 - 20] = z;   // next enc input
                cat2v[r2] = z;                                        // dec input (last level wins)
                if (lev < 3) ostash[28 + lev * 28 + r2] = fin;        // mu_e row
            } else if (c2 == 4 && lev < 3) {
                ostash[252 + lev * 28 + r2] = fin;                    // logstd row
            }
        }
        __syncthreads();
    }

    // ---- decoder init: h = relu(W3 @ [d4|y] + b3), 1 lane/row on waves 2-3 ----
    if (tid >= 128 && tid < 228) {
        float s = dot_rl<10>(w3s, cat2v);
        ((float*)h_lds)[h3o] = fmaxf(s + b3r, 0.f);
    }
    __syncthreads();

    // ---- decoder: 4 steps x 2 stages (fc5/fc6 deferred to batch) ----
    for (int s3 = 3; s3 >= 0; s3--) {
        // A: rec = sigmoid(W4 @ h + b4); stash rec; quant(rec) -> cat2v
        if (tid < 112) {
            float s = dot_rl<7>(w4s, h_lds[g4]);
            s += __shfl_xor(s, 1);
            s += __shfl_xor(s, 2);
            if (g4 == 0) {
                float rv = sigmoid_f(s + b4r);
                rec4[s3][r4] = rv;
                cat2v[r4] = quant_f(rv);
                if (s3 == 0) ostash[r4] = rv;      // recon0
            }
        }
        __syncthreads();

        // F: next h = relu(W3 @ cat2 + b3) (waves 2-3)
        if (s3 > 0) {
            if (tid >= 128 && tid < 228) {
                float s = dot_rl<10>(w3s, cat2v);
                ((float*)h_lds)[h3o] = fmaxf(s + b3r, 0.f);
            }
            __syncthreads();
        }
    }

    // ---- batched fc5: all 4 steps' t = W5 @ rec + b5 (400 outputs, 2 per lane) ----
    if (tid < 200) {
        float sA = dot_rl<7>(w5f, rec4[s3lo]);
        float sB = dot_rl<7>(w5f, rec4[s3lo + 2]);
        t_b[s3lo][j5]     = sA + b5r;
        t_b[s3lo + 2][j5] = sB + b5r;
    }
    __syncthreads();

    // ---- batched fc6: mu_d rows for all 4 steps (112 outputs, 2-lane K-split) ----
    if (tid < 224) {
        float s = dot_rl<13>(w6h, &t_b[s36][52 * p6]);
        s += __shfl_xor(s, 1);
        if (p6 == 0) ostash[140 + s36 * 28 + i6] = s + b6r;
    }
    __syncthreads();

    // ---- epilogue: single coalesced output write ----
    if (tid < 91) ((float4*)out)[tid] = ((const float4*)ostash)[tid];
}

extern "C" void kernel_launch(void* const* d_in, const int* in_sizes, int n_in,
                              void* d_out, int out_size, void* d_ws, size_t ws_size,
                              hipStream_t stream) {
    const float* x   = (const float*)d_in[0];
    const float* y   = (const float*)d_in[1];
    const float* eps = (const float*)d_in[2];
    const float* W1  = (const float*)d_in[3];
    const float* b1  = (const float*)d_in[4];
    const float* W2m = (const float*)d_in[5];
    const float* b2m = (const float*)d_in[6];
    const float* W2s = (const float*)d_in[7];
    const float* b2s = (const float*)d_in[8];
    const float* W3  = (const float*)d_in[9];
    const float* b3  = (const float*)d_in[10];
    const float* W4  = (const float*)d_in[11];
    const float* b4  = (const float*)d_in[12];
    const float* W5  = (const float*)d_in[13];
    const float* b5  = (const float*)d_in[14];
    const float* W6  = (const float*)d_in[15];
    const float* b6  = (const float*)d_in[16];
    float* out = (float*)d_out;

    cvae_kernel<<<1, NT, 0, stream>>>(x, y, eps, W1, b1, W2m, b2m, W2s, b2s,
                                      W3, b3, W4, b4, W5, b5, W6, b6, out);
}